// Round 2
// baseline (226.807 us; speedup 1.0000x reference)
//
#include <hip/hip_runtime.h>

// DilatedAttention: b=2,h=16,s=8192,d=64; W=[4,8,16], R=[1,2,4] -> L=4 for all
// groups. A 32-position span is self-contained for all three groups. fp32.
//
// V3: back to 8192 independent one-span blocks (V2 showed cross-block overlap
// beats intra-block pipelining). LDS now holds ONLY V (the one tensor with
// real cross-wave reuse) + probs: 9 KB/block -> 8 blocks/CU (wave-limited
// max). q,k are read straight from global in phase 2 (4-way dup served by
// L1; HBM bytes unchanged). This deletes the first barrier entirely: the V
// loads' HBM latency hides under phase 2's dot chain; ONE __syncthreads per
// block.

#define SPAN 32
#define D    64
#define S_SEQ 8192

__device__ __forceinline__ void acc_group(float4& acc, const float* lv,
                                          const float4 pr, float wg,
                                          int kb, int stride, int dd) {
    float p0 = pr.x * wg;
    float p1 = pr.y * wg;
    float p2 = pr.z * wg;
    float p3 = pr.w * wg;
    const float* vr = &lv[kb * D + dd];
    float4 v0 = *(const float4*)(vr);
    float4 v1 = *(const float4*)(vr + stride * D);
    float4 v2 = *(const float4*)(vr + 2 * stride * D);
    float4 v3 = *(const float4*)(vr + 3 * stride * D);
    acc.x += p0 * v0.x + p1 * v1.x + p2 * v2.x + p3 * v3.x;
    acc.y += p0 * v0.y + p1 * v1.y + p2 * v2.y + p3 * v3.y;
    acc.z += p0 * v0.z + p1 * v1.z + p2 * v2.z + p3 * v3.z;
    acc.w += p0 * v0.w + p1 * v1.w + p2 * v2.w + p3 * v3.w;
}

__global__ __launch_bounds__(256, 8) void dilated_attn_kernel(
    const float* __restrict__ q,
    const float* __restrict__ k,
    const float* __restrict__ v,
    const float* __restrict__ alpha,
    float* __restrict__ out) {
    __shared__ float lv[SPAN * D];            // 8 KB, unpadded (see conflict note)
    __shared__ __align__(16) float pl[224];   // 56 rows x 4 probs

    const int tid = threadIdx.x;
    const int nspan = S_SEQ / SPAN;                 // 256
    const int bh = blockIdx.x / nspan;
    const int span = blockIdx.x % nspan;
    const long long rowbase = (long long)bh * S_SEQ + (long long)span * SPAN;

    // softmax(alpha) over 3 groups (redundant per-thread, trivial)
    float a0 = alpha[0];
    float a1 = alpha[1];
    float a2 = alpha[2];
    float am = fmaxf(a0, fmaxf(a1, a2));
    float e0 = __expf(a0 - am), e1 = __expf(a1 - am), e2 = __expf(a2 - am);
    float inv = 1.0f / (e0 + e1 + e2);
    const float w0 = e0 * inv, w1 = e1 * inv, w2 = e2 * inv;

    // ---- V prefetch into regs, coalesced float4 (issued before phase 2;
    // latency hides under the q.k dot chain) ----
    const int r0 = tid >> 4;        // 0..15
    const int r1 = r0 + 16;         // 16..31
    const int c4 = tid & 15;        // float4 chunk within row
    const float4* v4 = (const float4*)v;
    float4 Rv0 = v4[(rowbase + r0) * (D / 4) + c4];
    float4 Rv1 = v4[(rowbase + r1) * (D / 4) + c4];

    // ---- Phase 2: 224 scores = 56 query rows x 4 keys, q/k from GLOBAL.
    // Each thread streams two contiguous 256B rows; quad-siblings read the
    // same q row (L1 broadcast). Softmax over 4 lanes via shfl_xor. ----
    if (tid < 224) {
        const int row = tid >> 2;  // 0..55
        const int j   = tid & 3;
        int w, r, win, i;
        if (row < 32)      { w = 4;  r = 1; win = row >> 2;        i = row & 3; }
        else if (row < 48) { w = 8;  r = 2; win = (row - 32) >> 2; i = (row - 32) & 3; }
        else               { w = 16; r = 4; win = (row - 48) >> 2; i = (row - 48) & 3; }
        const int pq = win * w + i * r;
        const int pk = win * w + j * r;
        const float4* qg = (const float4*)q + (rowbase + pq) * (D / 4);
        const float4* kg = (const float4*)k + (rowbase + pk) * (D / 4);
        float acc4[4] = {0.f, 0.f, 0.f, 0.f};  // 4 chains -> ILP
#pragma unroll
        for (int c = 0; c < 16; ++c) {
            float4 a = qg[c];
            float4 b = kg[c];
            acc4[c & 3] += a.x * b.x + a.y * b.y + a.z * b.z + a.w * b.w;
        }
        float s = (acc4[0] + acc4[1]) + (acc4[2] + acc4[3]);
        s *= 0.125f;  // d^-0.5
        float m = fmaxf(s, __shfl_xor(s, 1));
        m = fmaxf(m, __shfl_xor(m, 2));
        float p = __expf(s - m);
        float sum = p + __shfl_xor(p, 1);
        sum += __shfl_xor(sum, 2);
        pl[tid] = p / sum;   // pl[row*4 + j]
    }

    // ---- stage V regs -> LDS (loads have long since returned) ----
    *(float4*)&lv[r0 * D + c4 * 4] = Rv0;
    *(float4*)&lv[r1 * D + c4 * 4] = Rv1;

    __syncthreads();  // the ONLY barrier: covers pl writes + lv writes

    // ---- Phase 3: PV + mix. Wave wv handles pos ≡ wv (mod 4) so the
    // group-participation predicate is wave-uniform (no divergence).
    // Conflict note (PD=64): each ds_read_b128 spreads 64 lanes over 16
    // chunk columns x 4 rows -> <=2 distinct addrs/bank (free, m136). ----
    const int wv   = tid >> 6;        // 0..3
    const int l    = tid & 63;
    const int dd   = (l & 15) << 2;   // d offset, float4 granule
    const int psub = l >> 4;          // 0..3

#pragma unroll
    for (int s2 = 0; s2 < 2; ++s2) {
        const int pos = wv + 16 * s2 + 4 * psub;   // pos % 4 == wv
        float4 acc = make_float4(0.f, 0.f, 0.f, 0.f);

        // group 0 (w=4, r=1): every position; prob row == pos
        {
            float4 pr = *(const float4*)&pl[pos * 4];
            acc_group(acc, lv, pr, w0, pos & ~3, 1, dd);
        }
        if ((wv & 1) == 0) {  // group 1 (w=8, r=2): pos even
            const int prow = 32 + ((pos >> 3) << 2) + ((pos & 7) >> 1);
            float4 pr = *(const float4*)&pl[prow * 4];
            acc_group(acc, lv, pr, w1, pos & ~7, 2, dd);
        }
        if (wv == 0) {        // group 2 (w=16, r=4): pos % 4 == 0
            const int prow = 48 + ((pos >> 4) << 2) + ((pos & 15) >> 2);
            float4 pr = *(const float4*)&pl[prow * 4];
            acc_group(acc, lv, pr, w2, pos & ~15, 4, dd);
        }

        *(float4*)&out[(rowbase + pos) * D + dd] = acc;
    }
}

extern "C" void kernel_launch(void* const* d_in, const int* in_sizes, int n_in,
                              void* d_out, int out_size, void* d_ws, size_t ws_size,
                              hipStream_t stream) {
    const float* q = (const float*)d_in[0];
    const float* k = (const float*)d_in[1];
    const float* v = (const float*)d_in[2];
    const float* alpha = (const float*)d_in[3];
    float* out = (float*)d_out;

    const int BH = in_sizes[0] / (S_SEQ * D);      // b*h = 32
    dim3 grid(BH * (S_SEQ / SPAN));                 // 8192 blocks
    dim3 block(256);
    hipLaunchKernelGGL(dilated_attn_kernel, grid, block, 0, stream,
                       q, k, v, alpha, out);
}

// Round 3
// 225.513 us; speedup vs baseline: 1.0057x; 1.0057x over previous
//
#include <hip/hip_runtime.h>

// DilatedAttention: b=2,h=16,s=8192,d=64; W=[4,8,16], R=[1,2,4] -> L=4 for all
// groups. A 32-position span is self-contained for all three groups. fp32.
//
// V4 = V3 + two changes:
//  (1) NON-TEMPORAL stores for out. Working set q+k+v+out = 266 MB > 256 MB
//      L3: the write stream thrashes the L3 and evicts q/k/v (FETCH_SIZE
//      showed 98 MB of HBM re-fetch). out is never re-read -> nt store keeps
//      q,k,v fully L3-resident, halving average read latency (the term that
//      caps concurrency-limited BW).
//  (2) Batched phase-2 loads (4 q + 4 k float4 per round, static-indexed):
//      V3 compiled to 28 VGPRs = tiny load/wait rounds; 32 data regs of
//      depth halves the number of full-latency rounds (fits 64-VGPR budget).

#define SPAN 32
#define D    64
#define S_SEQ 8192

typedef float f4 __attribute__((ext_vector_type(4)));

__device__ __forceinline__ void acc_group(float4& acc, const float* lv,
                                          const float4 pr, float wg,
                                          int kb, int stride, int dd) {
    float p0 = pr.x * wg;
    float p1 = pr.y * wg;
    float p2 = pr.z * wg;
    float p3 = pr.w * wg;
    const float* vr = &lv[kb * D + dd];
    float4 v0 = *(const float4*)(vr);
    float4 v1 = *(const float4*)(vr + stride * D);
    float4 v2 = *(const float4*)(vr + 2 * stride * D);
    float4 v3 = *(const float4*)(vr + 3 * stride * D);
    acc.x += p0 * v0.x + p1 * v1.x + p2 * v2.x + p3 * v3.x;
    acc.y += p0 * v0.y + p1 * v1.y + p2 * v2.y + p3 * v3.y;
    acc.z += p0 * v0.z + p1 * v1.z + p2 * v2.z + p3 * v3.z;
    acc.w += p0 * v0.w + p1 * v1.w + p2 * v2.w + p3 * v3.w;
}

__global__ __launch_bounds__(256, 8) void dilated_attn_kernel(
    const float* __restrict__ q,
    const float* __restrict__ k,
    const float* __restrict__ v,
    const float* __restrict__ alpha,
    float* __restrict__ out) {
    __shared__ float lv[SPAN * D];            // 8 KB, unpadded (conflict-free, V3)
    __shared__ __align__(16) float pl[224];   // 56 rows x 4 probs

    const int tid = threadIdx.x;
    const int nspan = S_SEQ / SPAN;                 // 256
    const int bh = blockIdx.x / nspan;
    const int span = blockIdx.x % nspan;
    const long long rowbase = (long long)bh * S_SEQ + (long long)span * SPAN;

    // softmax(alpha) over 3 groups (redundant per-thread, trivial)
    float a0 = alpha[0];
    float a1 = alpha[1];
    float a2 = alpha[2];
    float am = fmaxf(a0, fmaxf(a1, a2));
    float e0 = __expf(a0 - am), e1 = __expf(a1 - am), e2 = __expf(a2 - am);
    float inv = 1.0f / (e0 + e1 + e2);
    const float w0 = e0 * inv, w1 = e1 * inv, w2 = e2 * inv;

    // ---- V prefetch into regs, coalesced float4 (issued before phase 2;
    // latency hides under the q.k dot chain) ----
    const int r0 = tid >> 4;        // 0..15
    const int r1 = r0 + 16;         // 16..31
    const int c4 = tid & 15;        // float4 chunk within row
    const float4* v4p = (const float4*)v;
    float4 Rv0 = v4p[(rowbase + r0) * (D / 4) + c4];
    float4 Rv1 = v4p[(rowbase + r1) * (D / 4) + c4];

    // ---- Phase 2: 224 scores = 56 query rows x 4 keys, q/k from GLOBAL
    // (L1/L2 broadcast of the 4-way dup; reads are L3 hits once out stops
    // thrashing the cache). Batched 4q+4k loads for MLP. ----
    if (tid < 224) {
        const int row = tid >> 2;  // 0..55
        const int j   = tid & 3;
        int w, r, win, i;
        if (row < 32)      { w = 4;  r = 1; win = row >> 2;        i = row & 3; }
        else if (row < 48) { w = 8;  r = 2; win = (row - 32) >> 2; i = (row - 32) & 3; }
        else               { w = 16; r = 4; win = (row - 48) >> 2; i = (row - 48) & 3; }
        const int pq = win * w + i * r;
        const int pk = win * w + j * r;
        const float4* qg = (const float4*)q + (rowbase + pq) * (D / 4);
        const float4* kg = (const float4*)k + (rowbase + pk) * (D / 4);
        float acc4[4] = {0.f, 0.f, 0.f, 0.f};  // 4 chains -> ILP
#pragma unroll
        for (int b = 0; b < 4; ++b) {
            float4 qa[4], ka[4];
#pragma unroll
            for (int c = 0; c < 4; ++c) {       // 8 loads issued back-to-back
                qa[c] = qg[b * 4 + c];
                ka[c] = kg[b * 4 + c];
            }
#pragma unroll
            for (int c = 0; c < 4; ++c) {
                acc4[c] += qa[c].x * ka[c].x + qa[c].y * ka[c].y +
                           qa[c].z * ka[c].z + qa[c].w * ka[c].w;
            }
        }
        float s = (acc4[0] + acc4[1]) + (acc4[2] + acc4[3]);
        s *= 0.125f;  // d^-0.5
        float m = fmaxf(s, __shfl_xor(s, 1));
        m = fmaxf(m, __shfl_xor(m, 2));
        float p = __expf(s - m);
        float sum = p + __shfl_xor(p, 1);
        sum += __shfl_xor(sum, 2);
        pl[tid] = p / sum;   // pl[row*4 + j]
    }

    // ---- stage V regs -> LDS (loads have long since returned) ----
    *(float4*)&lv[r0 * D + c4 * 4] = Rv0;
    *(float4*)&lv[r1 * D + c4 * 4] = Rv1;

    __syncthreads();  // the ONLY barrier: covers pl writes + lv writes

    // ---- Phase 3: PV + mix. Wave wv handles pos ≡ wv (mod 4); nt stores. ----
    const int wv   = tid >> 6;        // 0..3
    const int l    = tid & 63;
    const int dd   = (l & 15) << 2;   // d offset, float4 granule
    const int psub = l >> 4;          // 0..3

#pragma unroll
    for (int s2 = 0; s2 < 2; ++s2) {
        const int pos = wv + 16 * s2 + 4 * psub;   // pos % 4 == wv
        float4 acc = make_float4(0.f, 0.f, 0.f, 0.f);

        // group 0 (w=4, r=1): every position; prob row == pos
        {
            float4 pr = *(const float4*)&pl[pos * 4];
            acc_group(acc, lv, pr, w0, pos & ~3, 1, dd);
        }
        if ((wv & 1) == 0) {  // group 1 (w=8, r=2): pos even
            const int prow = 32 + ((pos >> 3) << 2) + ((pos & 7) >> 1);
            float4 pr = *(const float4*)&pl[prow * 4];
            acc_group(acc, lv, pr, w1, pos & ~7, 2, dd);
        }
        if (wv == 0) {        // group 2 (w=16, r=4): pos % 4 == 0
            const int prow = 48 + ((pos >> 4) << 2) + ((pos & 15) >> 2);
            float4 pr = *(const float4*)&pl[prow * 4];
            acc_group(acc, lv, pr, w2, pos & ~15, 4, dd);
        }

        // non-temporal: out is never re-read; keep it OUT of L3 so q,k,v
        // (201 MB) stay fully resident in the 256 MB Infinity Cache.
        f4 o = {acc.x, acc.y, acc.z, acc.w};
        __builtin_nontemporal_store(o, (f4*)&out[(rowbase + pos) * D + dd]);
    }
}

extern "C" void kernel_launch(void* const* d_in, const int* in_sizes, int n_in,
                              void* d_out, int out_size, void* d_ws, size_t ws_size,
                              hipStream_t stream) {
    const float* q = (const float*)d_in[0];
    const float* k = (const float*)d_in[1];
    const float* v = (const float*)d_in[2];
    const float* alpha = (const float*)d_in[3];
    float* out = (float*)d_out;

    const int BH = in_sizes[0] / (S_SEQ * D);      // b*h = 32
    dim3 grid(BH * (S_SEQ / SPAN));                 // 8192 blocks
    dim3 block(256);
    hipLaunchKernelGGL(dilated_attn_kernel, grid, block, 0, stream,
                       q, k, v, alpha, out);
}